// Round 1
// baseline (640.618 us; speedup 1.0000x reference)
//
#include <hip/hip_runtime.h>
#include <math.h>

// Problem: ChebConv (K=4) GNN head.
// N=50000 nodes, E=800000 edges, F_IN=64, H=128.
// Strategy: build CSR per call (counting sort, int atomics only), then 3
// gather-only SPMMs (wave-per-row, lane=feature), then fused GEMM+tanh+dot.

#define FIN 64
#define HDIM 128

__global__ void count_deg(const int* __restrict__ row, int* __restrict__ deg, int E) {
    int e = blockIdx.x * blockDim.x + threadIdx.x;
    if (e < E) atomicAdd(&deg[row[e]], 1);
}

__global__ void make_dinv(const int* __restrict__ deg, float* __restrict__ dinv, int n) {
    int i = blockIdx.x * blockDim.x + threadIdx.x;
    if (i < n) {
        int d = deg[i];
        dinv[i] = (d > 0) ? rsqrtf((float)d) : 0.f;
    }
}

// Per-block exclusive scan (Hillis-Steele over 1024 elems) + block totals.
__global__ void scan_local(const int* __restrict__ in, int* __restrict__ out,
                           int* __restrict__ bsum, int n) {
    __shared__ int buf[1024];
    int tid = threadIdx.x;
    int gid = blockIdx.x * 1024 + tid;
    int v = (gid < n) ? in[gid] : 0;
    int x = v;
    buf[tid] = x;
    __syncthreads();
    for (int off = 1; off < 1024; off <<= 1) {
        int t = (tid >= off) ? buf[tid - off] : 0;
        __syncthreads();
        x += t;
        buf[tid] = x;
        __syncthreads();
    }
    if (gid < n) out[gid] = x - v;              // exclusive scan within block
    if (tid == 1023) bsum[blockIdx.x] = x;      // block total
}

__global__ void scan_bsums(int* bsum, int nb) {
    if (blockIdx.x == 0 && threadIdx.x == 0) {
        int acc = 0;
        for (int b = 0; b < nb; ++b) { int t = bsum[b]; bsum[b] = acc; acc += t; }
    }
}

__global__ void scan_finish(int* __restrict__ rowptr, const int* __restrict__ bsum,
                            int* __restrict__ cursor, int n, int E) {
    int i = blockIdx.x * blockDim.x + threadIdx.x;
    if (i < n) {
        int v = rowptr[i] + bsum[i >> 10];
        rowptr[i] = v;
        cursor[i] = v;
    } else if (i == n) {
        rowptr[n] = E;
    }
}

__global__ void scatter_edges(const int* __restrict__ row, const int* __restrict__ col,
                              const float* __restrict__ dinv, int* __restrict__ cursor,
                              int* __restrict__ col_s, float* __restrict__ ew_s, int E) {
    int e = blockIdx.x * blockDim.x + threadIdx.x;
    if (e < E) {
        int r = row[e], c = col[e];
        int p = atomicAdd(&cursor[r], 1);
        col_s[p] = c;
        ew_s[p] = -dinv[r] * dinv[c];   // L_hat = -D^-1/2 A D^-1/2
    }
}

// out[r][lane] = scale * sum_{p in row r} ew[p] * in[col[p]][lane]  - prev[r][lane]
// One wave per row; lane = feature (FIN==64 exactly one wave). Gather-only.
__global__ void spmm_csr(const int* __restrict__ rowptr, const int* __restrict__ cols,
                         const float* __restrict__ ews, const float* __restrict__ in,
                         const float* __restrict__ prev, float scale,
                         float* __restrict__ out, int n) {
    int lane = threadIdx.x & 63;
    int r = (blockIdx.x * blockDim.x + threadIdx.x) >> 6;
    if (r >= n) return;
    int s = rowptr[r], e = rowptr[r + 1];
    float acc = 0.f;
    for (int p = s; p < e; ++p) {
        int c = cols[p];
        float w = ews[p];
        acc = fmaf(w, in[c * FIN + lane], acc);
    }
    float res = scale * acc;
    if (prev) res -= prev[r * FIN + lane];
    out[r * FIN + lane] = res;
}

// out[n] = final_b + sum_h final_w[h] * tanh( cheb_b[h] + sum_k Tx_k[n,:] @ W[k][:,h] )
// Thread-per-node, acc[128] in VGPRs; W[k] (32 KB) staged in LDS per k-step
// (reads are wave-uniform -> broadcast, conflict-free).
__global__ __launch_bounds__(64) void gemm_final(
        const float* __restrict__ tx0, const float* __restrict__ tx1,
        const float* __restrict__ tx2, const float* __restrict__ tx3,
        const float* __restrict__ W,       // [4, FIN, HDIM]
        const float* __restrict__ cheb_b, const float* __restrict__ fw,
        const float* __restrict__ fb, float* __restrict__ out, int n) {
    __shared__ float wk[FIN * HDIM];     // 32 KB
    __shared__ float fwl[HDIM];
    __shared__ float cbl[HDIM];
    int tid = threadIdx.x;
    int node = blockIdx.x * 64 + tid;

    for (int i = tid; i < HDIM; i += 64) { fwl[i] = fw[i]; cbl[i] = cheb_b[i]; }

    float acc[HDIM];
#pragma unroll
    for (int h = 0; h < HDIM; ++h) acc[h] = 0.f;

    const float* txs[4] = {tx0, tx1, tx2, tx3};
    for (int k = 0; k < 4; ++k) {
        __syncthreads();
        const float4* src = (const float4*)(W + k * FIN * HDIM);
        float4* dst = (float4*)wk;
        for (int i = tid; i < FIN * HDIM / 4; i += 64) dst[i] = src[i];
        __syncthreads();
        if (node < n) {
            const float* x = txs[k] + (size_t)node * FIN;
            for (int f4 = 0; f4 < FIN; f4 += 4) {
                float4 xv = *(const float4*)(x + f4);
                float xs[4] = {xv.x, xv.y, xv.z, xv.w};
#pragma unroll
                for (int j = 0; j < 4; ++j) {
                    float s = xs[j];
                    const float* wr = &wk[(f4 + j) * HDIM];
#pragma unroll
                    for (int h = 0; h < HDIM; ++h) acc[h] = fmaf(s, wr[h], acc[h]);
                }
            }
        }
    }
    if (node < n) {
        float s = 0.f;
#pragma unroll
        for (int h = 0; h < HDIM; ++h) {
            float v = tanhf(acc[h] + cbl[h]);
            s = fmaf(v, fwl[h], s);
        }
        out[node] = s + fb[0];
    }
}

extern "C" void kernel_launch(void* const* d_in, const int* in_sizes, int n_in,
                              void* d_out, int out_size, void* d_ws, size_t ws_size,
                              hipStream_t stream) {
    const float* features = (const float*)d_in[0];
    const int*   edge_index = (const int*)d_in[1];
    const float* cheb_w  = (const float*)d_in[2];
    const float* cheb_b  = (const float*)d_in[3];
    const float* final_w = (const float*)d_in[4];
    const float* final_b = (const float*)d_in[5];
    int N = in_sizes[0] / FIN;
    int E = in_sizes[1] / 2;
    const int* row = edge_index;        // edge_index[0, :]
    const int* col = edge_index + E;    // edge_index[1, :]

    // workspace layout (all 256 B aligned); total ~45.6 MB
    char* p = (char*)d_ws;
    auto alloc = [&](size_t bytes) {
        char* r = p;
        p += (bytes + 255) & ~(size_t)255;
        return r;
    };
    int*   deg    = (int*)alloc((size_t)N * 4);
    float* dinv   = (float*)alloc((size_t)N * 4);
    int*   rowptr = (int*)alloc((size_t)(N + 1) * 4);
    int*   cursor = (int*)alloc((size_t)N * 4);
    int*   bsum   = (int*)alloc(1024 * 4);
    int*   col_s  = (int*)alloc((size_t)E * 4);
    float* ew_s   = (float*)alloc((size_t)E * 4);
    float* tx1    = (float*)alloc((size_t)N * FIN * 4);
    float* tx2    = (float*)alloc((size_t)N * FIN * 4);
    float* tx3    = (float*)alloc((size_t)N * FIN * 4);

    hipMemsetAsync(deg, 0, (size_t)N * 4, stream);
    count_deg<<<(E + 255) / 256, 256, 0, stream>>>(row, deg, E);
    make_dinv<<<(N + 255) / 256, 256, 0, stream>>>(deg, dinv, N);
    int nb = (N + 1023) / 1024;
    scan_local<<<nb, 1024, 0, stream>>>(deg, rowptr, bsum, N);
    scan_bsums<<<1, 64, 0, stream>>>(bsum, nb);
    scan_finish<<<(N + 1 + 255) / 256, 256, 0, stream>>>(rowptr, bsum, cursor, N, E);
    scatter_edges<<<(E + 255) / 256, 256, 0, stream>>>(row, col, dinv, cursor, col_s, ew_s, E);

    int spmm_blocks = (N * 64 + 255) / 256;
    // Tx1 = L_hat @ x
    spmm_csr<<<spmm_blocks, 256, 0, stream>>>(rowptr, col_s, ew_s, features, nullptr, 1.f, tx1, N);
    // Tx2 = 2 * L_hat @ Tx1 - Tx0
    spmm_csr<<<spmm_blocks, 256, 0, stream>>>(rowptr, col_s, ew_s, tx1, features, 2.f, tx2, N);
    // Tx3 = 2 * L_hat @ Tx2 - Tx1
    spmm_csr<<<spmm_blocks, 256, 0, stream>>>(rowptr, col_s, ew_s, tx2, tx1, 2.f, tx3, N);

    gemm_final<<<(N + 63) / 64, 64, 0, stream>>>(features, tx1, tx2, tx3, cheb_w,
                                                 cheb_b, final_w, final_b,
                                                 (float*)d_out, N);
}

// Round 2
// 318.959 us; speedup vs baseline: 2.0085x; 2.0085x over previous
//
#include <hip/hip_runtime.h>
#include <math.h>

// ChebConv (K=4) GNN head. N=50000, E=800000, F_IN=64, H=128.
// R2: register-tiled fp32 GEMM (8x8 microtile/thread), SPMM with 4 rows/wave
// float4 gathers and packed (col,weight) edge metadata.

#define FIN 64
#define HDIM 128

__global__ void count_deg(const int* __restrict__ row, int* __restrict__ deg, int E) {
    int e = blockIdx.x * blockDim.x + threadIdx.x;
    if (e < E) atomicAdd(&deg[row[e]], 1);
}

__global__ void make_dinv(const int* __restrict__ deg, float* __restrict__ dinv, int n) {
    int i = blockIdx.x * blockDim.x + threadIdx.x;
    if (i < n) {
        int d = deg[i];
        dinv[i] = (d > 0) ? rsqrtf((float)d) : 0.f;
    }
}

// Per-block exclusive scan (Hillis-Steele over 1024 elems) + block totals.
__global__ void scan_local(const int* __restrict__ in, int* __restrict__ out,
                           int* __restrict__ bsum, int n) {
    __shared__ int buf[1024];
    int tid = threadIdx.x;
    int gid = blockIdx.x * 1024 + tid;
    int v = (gid < n) ? in[gid] : 0;
    int x = v;
    buf[tid] = x;
    __syncthreads();
    for (int off = 1; off < 1024; off <<= 1) {
        int t = (tid >= off) ? buf[tid - off] : 0;
        __syncthreads();
        x += t;
        buf[tid] = x;
        __syncthreads();
    }
    if (gid < n) out[gid] = x - v;
    if (tid == 1023) bsum[blockIdx.x] = x;
}

__global__ void scan_bsums(int* bsum, int nb) {
    if (blockIdx.x == 0 && threadIdx.x == 0) {
        int acc = 0;
        for (int b = 0; b < nb; ++b) { int t = bsum[b]; bsum[b] = acc; acc += t; }
    }
}

__global__ void scan_finish(int* __restrict__ rowptr, const int* __restrict__ bsum,
                            int* __restrict__ cursor, int n, int E) {
    int i = blockIdx.x * blockDim.x + threadIdx.x;
    if (i < n) {
        int v = rowptr[i] + bsum[i >> 10];
        rowptr[i] = v;
        cursor[i] = v;
    } else if (i == n) {
        rowptr[n] = E;
    }
}

// Pack (col, bitcast(weight)) into one int2 per edge -> single 8B load in spmm.
__global__ void scatter_edges(const int* __restrict__ row, const int* __restrict__ col,
                              const float* __restrict__ dinv, int* __restrict__ cursor,
                              int2* __restrict__ epk, int E) {
    int e = blockIdx.x * blockDim.x + threadIdx.x;
    if (e < E) {
        int r = row[e], c = col[e];
        int p = atomicAdd(&cursor[r], 1);
        float w = -dinv[r] * dinv[c];   // L_hat = -D^-1/2 A D^-1/2
        epk[p] = make_int2(c, __float_as_int(w));
    }
}

// 4 rows per wave, 16 lanes/row, float4 per lane (256B per row gather).
// out[r] = scale * sum_p ew[p]*in[col[p]]  (- prev[r])
__global__ __launch_bounds__(256) void spmm_csr(
        const int* __restrict__ rowptr, const int2* __restrict__ epk,
        const float4* __restrict__ in4, const float4* __restrict__ prev4,
        float scale, float4* __restrict__ out4, int n) {
    int lane = threadIdx.x & 63;
    int wid = (blockIdx.x * blockDim.x + threadIdx.x) >> 6;
    int li = lane & 15, g = lane >> 4;
    int r = wid * 4 + g;
    if (r >= n) return;
    int s = rowptr[r], e = rowptr[r + 1];
    float4 acc = make_float4(0.f, 0.f, 0.f, 0.f);
    int p = s;
    for (; p + 2 <= e; p += 2) {
        int2 m0 = epk[p];
        int2 m1 = epk[p + 1];
        float4 v0 = in4[(size_t)m0.x * 16 + li];
        float4 v1 = in4[(size_t)m1.x * 16 + li];
        float w0 = __int_as_float(m0.y);
        float w1 = __int_as_float(m1.y);
        acc.x = fmaf(w0, v0.x, acc.x); acc.y = fmaf(w0, v0.y, acc.y);
        acc.z = fmaf(w0, v0.z, acc.z); acc.w = fmaf(w0, v0.w, acc.w);
        acc.x = fmaf(w1, v1.x, acc.x); acc.y = fmaf(w1, v1.y, acc.y);
        acc.z = fmaf(w1, v1.z, acc.z); acc.w = fmaf(w1, v1.w, acc.w);
    }
    if (p < e) {
        int2 m0 = epk[p];
        float4 v0 = in4[(size_t)m0.x * 16 + li];
        float w0 = __int_as_float(m0.y);
        acc.x = fmaf(w0, v0.x, acc.x); acc.y = fmaf(w0, v0.y, acc.y);
        acc.z = fmaf(w0, v0.z, acc.z); acc.w = fmaf(w0, v0.w, acc.w);
    }
    float4 res;
    res.x = scale * acc.x; res.y = scale * acc.y;
    res.z = scale * acc.z; res.w = scale * acc.w;
    if (prev4) {
        float4 pv = prev4[(size_t)r * 16 + li];
        res.x -= pv.x; res.y -= pv.y; res.z -= pv.z; res.w -= pv.w;
    }
    out4[(size_t)r * 16 + li] = res;
}

// Register-tiled GEMM: C[128 nodes x 128 h] per block, 256 threads (16x16),
// 8x8 microtile/thread. A = [Tx0|Tx1|Tx2|Tx3] (k=256), B = cheb_w (256x128).
// Epilogue: tanh + dot with final_w, __shfl_xor reduce over 16 lanes.
__global__ __launch_bounds__(256) void gemm_final(
        const float* __restrict__ tx0, const float* __restrict__ tx1,
        const float* __restrict__ tx2, const float* __restrict__ tx3,
        const float* __restrict__ W,       // [4, FIN, HDIM]
        const float* __restrict__ cheb_b, const float* __restrict__ fw,
        const float* __restrict__ fb, float* __restrict__ out, int n) {
    __shared__ float As[64 * 129];     // A-tile transposed: As[k][node], +1 pad
    __shared__ float Bs[64 * 128];     // B-tile: Bs[k][h]
    int tid = threadIdx.x;
    int tx = tid & 15, ty = tid >> 4;
    int nb0 = blockIdx.x * 128;

    float acc[8][8];
#pragma unroll
    for (int i = 0; i < 8; ++i)
#pragma unroll
        for (int j = 0; j < 8; ++j) acc[i][j] = 0.f;

    const float* txs[4] = {tx0, tx1, tx2, tx3};
    for (int c = 0; c < 4; ++c) {
        __syncthreads();
        // stage A chunk: 128 nodes x 64 k, transpose into As[k][node]
        {
            const float4* src = (const float4*)txs[c] + (size_t)nb0 * 16;
#pragma unroll
            for (int i = 0; i < 8; ++i) {
                int idx = tid + i * 256;        // float4 index, 2048 total
                int node = idx >> 4;
                int k4 = (idx & 15) * 4;
                float4 v = (nb0 + node < n) ? src[idx]
                                            : make_float4(0.f, 0.f, 0.f, 0.f);
                As[(k4 + 0) * 129 + node] = v.x;
                As[(k4 + 1) * 129 + node] = v.y;
                As[(k4 + 2) * 129 + node] = v.z;
                As[(k4 + 3) * 129 + node] = v.w;
            }
        }
        // stage B chunk: contiguous copy of W[c] (64x128)
        {
            const float4* wsrc = (const float4*)(W + c * FIN * HDIM);
            float4* wdst = (float4*)Bs;
#pragma unroll
            for (int i = 0; i < 8; ++i) wdst[tid + i * 256] = wsrc[tid + i * 256];
        }
        __syncthreads();
#pragma unroll 4
        for (int k = 0; k < 64; ++k) {
            float av[8], bv[8];
            *(float4*)&av[0] = *(const float4*)&As[k * 129 + ty * 8];
            *(float4*)&av[4] = *(const float4*)&As[k * 129 + ty * 8 + 4];
            *(float4*)&bv[0] = *(const float4*)&Bs[k * 128 + tx * 8];
            *(float4*)&bv[4] = *(const float4*)&Bs[k * 128 + tx * 8 + 4];
#pragma unroll
            for (int i = 0; i < 8; ++i)
#pragma unroll
                for (int j = 0; j < 8; ++j)
                    acc[i][j] = fmaf(av[i], bv[j], acc[i][j]);
        }
    }
    // epilogue: per node, s = sum_h tanh(acc+cb[h]) * fw[h]; reduce over tx
    float cb[8], fwv[8];
#pragma unroll
    for (int j = 0; j < 8; ++j) {
        cb[j] = cheb_b[tx * 8 + j];
        fwv[j] = fw[tx * 8 + j];
    }
    float fb0 = fb[0];
#pragma unroll
    for (int i = 0; i < 8; ++i) {
        float s = 0.f;
#pragma unroll
        for (int j = 0; j < 8; ++j)
            s = fmaf(tanhf(acc[i][j] + cb[j]), fwv[j], s);
        // reduce across the 16 lanes (tx) that share this node row
        for (int m = 1; m < 16; m <<= 1) s += __shfl_xor(s, m, 64);
        if (tx == 0) {
            int node = nb0 + ty * 8 + i;
            if (node < n) out[node] = s + fb0;
        }
    }
}

extern "C" void kernel_launch(void* const* d_in, const int* in_sizes, int n_in,
                              void* d_out, int out_size, void* d_ws, size_t ws_size,
                              hipStream_t stream) {
    const float* features = (const float*)d_in[0];
    const int*   edge_index = (const int*)d_in[1];
    const float* cheb_w  = (const float*)d_in[2];
    const float* cheb_b  = (const float*)d_in[3];
    const float* final_w = (const float*)d_in[4];
    const float* final_b = (const float*)d_in[5];
    int N = in_sizes[0] / FIN;
    int E = in_sizes[1] / 2;
    const int* row = edge_index;        // edge_index[0, :]
    const int* col = edge_index + E;    // edge_index[1, :]

    char* p = (char*)d_ws;
    auto alloc = [&](size_t bytes) {
        char* r = p;
        p += (bytes + 255) & ~(size_t)255;
        return r;
    };
    int*   deg    = (int*)alloc((size_t)N * 4);
    float* dinv   = (float*)alloc((size_t)N * 4);
    int*   rowptr = (int*)alloc((size_t)(N + 1) * 4);
    int*   cursor = (int*)alloc((size_t)N * 4);
    int*   bsum   = (int*)alloc(1024 * 4);
    int2*  epk    = (int2*)alloc((size_t)E * 8);
    float* tx1    = (float*)alloc((size_t)N * FIN * 4);
    float* tx2    = (float*)alloc((size_t)N * FIN * 4);
    float* tx3    = (float*)alloc((size_t)N * FIN * 4);

    hipMemsetAsync(deg, 0, (size_t)N * 4, stream);
    count_deg<<<(E + 255) / 256, 256, 0, stream>>>(row, deg, E);
    make_dinv<<<(N + 255) / 256, 256, 0, stream>>>(deg, dinv, N);
    int nb = (N + 1023) / 1024;
    scan_local<<<nb, 1024, 0, stream>>>(deg, rowptr, bsum, N);
    scan_bsums<<<1, 64, 0, stream>>>(bsum, nb);
    scan_finish<<<(N + 1 + 255) / 256, 256, 0, stream>>>(rowptr, bsum, cursor, N, E);
    scatter_edges<<<(E + 255) / 256, 256, 0, stream>>>(row, col, dinv, cursor, epk, E);

    int waves = (N + 3) / 4;
    int spmm_blocks = (waves * 64 + 255) / 256;
    // Tx1 = L_hat @ x
    spmm_csr<<<spmm_blocks, 256, 0, stream>>>(rowptr, epk, (const float4*)features,
                                              nullptr, 1.f, (float4*)tx1, N);
    // Tx2 = 2 * L_hat @ Tx1 - Tx0
    spmm_csr<<<spmm_blocks, 256, 0, stream>>>(rowptr, epk, (const float4*)tx1,
                                              (const float4*)features, 2.f, (float4*)tx2, N);
    // Tx3 = 2 * L_hat @ Tx2 - Tx1
    spmm_csr<<<spmm_blocks, 256, 0, stream>>>(rowptr, epk, (const float4*)tx2,
                                              (const float4*)tx1, 2.f, (float4*)tx3, N);

    gemm_final<<<(N + 127) / 128, 256, 0, stream>>>(features, tx1, tx2, tx3, cheb_w,
                                                    cheb_b, final_w, final_b,
                                                    (float*)d_out, N);
}

// Round 3
// 279.603 us; speedup vs baseline: 2.2912x; 1.1408x over previous
//
#include <hip/hip_runtime.h>
#include <hip/hip_fp16.h>
#include <math.h>

// ChebConv (K=4) GNN head. N=50000, E=800000, F_IN=64, H=128.
// R3: fp16 storage for gather-side SPMM rows (halves L2/LLC gather traffic,
// fp32 accumulation), bank-conflict-free GEMM fragment layout (stride-4 h
// groups), 33KB LDS GEMM (4 blocks/CU).

#define FIN 64
#define HDIM 128

union U16 { uint4 u; __half2 h2[4]; };

__global__ void count_deg(const int* __restrict__ row, int* __restrict__ deg, int E) {
    int e = blockIdx.x * blockDim.x + threadIdx.x;
    if (e < E) atomicAdd(&deg[row[e]], 1);
}

__global__ void make_dinv(const int* __restrict__ deg, float* __restrict__ dinv, int n) {
    int i = blockIdx.x * blockDim.x + threadIdx.x;
    if (i < n) {
        int d = deg[i];
        dinv[i] = (d > 0) ? rsqrtf((float)d) : 0.f;
    }
}

// features fp32 -> fp16 rows
__global__ void cvt_feat(const float4* __restrict__ src, uint4* __restrict__ dst, int n8) {
    int i = blockIdx.x * blockDim.x + threadIdx.x;
    if (i >= n8) return;
    float4 a = src[i * 2], b = src[i * 2 + 1];
    U16 v;
    v.h2[0] = __float22half2_rn(make_float2(a.x, a.y));
    v.h2[1] = __float22half2_rn(make_float2(a.z, a.w));
    v.h2[2] = __float22half2_rn(make_float2(b.x, b.y));
    v.h2[3] = __float22half2_rn(make_float2(b.z, b.w));
    dst[i] = v.u;
}

// Per-block exclusive scan (Hillis-Steele over 1024 elems) + block totals.
__global__ void scan_local(const int* __restrict__ in, int* __restrict__ out,
                           int* __restrict__ bsum, int n) {
    __shared__ int buf[1024];
    int tid = threadIdx.x;
    int gid = blockIdx.x * 1024 + tid;
    int v = (gid < n) ? in[gid] : 0;
    int x = v;
    buf[tid] = x;
    __syncthreads();
    for (int off = 1; off < 1024; off <<= 1) {
        int t = (tid >= off) ? buf[tid - off] : 0;
        __syncthreads();
        x += t;
        buf[tid] = x;
        __syncthreads();
    }
    if (gid < n) out[gid] = x - v;
    if (tid == 1023) bsum[blockIdx.x] = x;
}

__global__ void scan_bsums(int* bsum, int nb) {
    if (blockIdx.x == 0 && threadIdx.x == 0) {
        int acc = 0;
        for (int b = 0; b < nb; ++b) { int t = bsum[b]; bsum[b] = acc; acc += t; }
    }
}

__global__ void scan_finish(int* __restrict__ rowptr, const int* __restrict__ bsum,
                            int* __restrict__ cursor, int n, int E) {
    int i = blockIdx.x * blockDim.x + threadIdx.x;
    if (i < n) {
        int v = rowptr[i] + bsum[i >> 10];
        rowptr[i] = v;
        cursor[i] = v;
    } else if (i == n) {
        rowptr[n] = E;
    }
}

__global__ void scatter_edges(const int* __restrict__ row, const int* __restrict__ col,
                              const float* __restrict__ dinv, int* __restrict__ cursor,
                              int2* __restrict__ epk, int E) {
    int e = blockIdx.x * blockDim.x + threadIdx.x;
    if (e < E) {
        int r = row[e], c = col[e];
        int p = atomicAdd(&cursor[r], 1);
        float w = -dinv[r] * dinv[c];   // L_hat = -D^-1/2 A D^-1/2
        epk[p] = make_int2(c, __float_as_int(w));
    }
}

// 8 rows/wave, 8 lanes/row, 16B (8 halfs) per lane. fp32 accumulate.
// out[r] = fp16( scale * sum_p ew[p]*in[col[p]] - prev[r] )
__global__ __launch_bounds__(256) void spmm_h(
        const int* __restrict__ rowptr, const int2* __restrict__ epk,
        const uint4* __restrict__ in8, const uint4* __restrict__ prev8,
        float scale, uint4* __restrict__ out8, int n) {
    int lane = threadIdx.x & 63;
    int wid = (blockIdx.x * blockDim.x + threadIdx.x) >> 6;
    int li = lane & 7, g = lane >> 3;
    int r = wid * 8 + g;
    if (r >= n) return;
    int s = rowptr[r], e = rowptr[r + 1];
    float acc[8];
#pragma unroll
    for (int j = 0; j < 8; ++j) acc[j] = 0.f;
    int p = s;
    for (; p + 2 <= e; p += 2) {
        int2 m0 = epk[p];
        int2 m1 = epk[p + 1];
        U16 v0, v1;
        v0.u = in8[(size_t)m0.x * 8 + li];
        v1.u = in8[(size_t)m1.x * 8 + li];
        float w0 = __int_as_float(m0.y);
        float w1 = __int_as_float(m1.y);
#pragma unroll
        for (int j = 0; j < 4; ++j) {
            float2 f0 = __half22float2(v0.h2[j]);
            float2 f1 = __half22float2(v1.h2[j]);
            acc[2 * j]     = fmaf(w0, f0.x, acc[2 * j]);
            acc[2 * j + 1] = fmaf(w0, f0.y, acc[2 * j + 1]);
            acc[2 * j]     = fmaf(w1, f1.x, acc[2 * j]);
            acc[2 * j + 1] = fmaf(w1, f1.y, acc[2 * j + 1]);
        }
    }
    if (p < e) {
        int2 m0 = epk[p];
        U16 v0;
        v0.u = in8[(size_t)m0.x * 8 + li];
        float w0 = __int_as_float(m0.y);
#pragma unroll
        for (int j = 0; j < 4; ++j) {
            float2 f0 = __half22float2(v0.h2[j]);
            acc[2 * j]     = fmaf(w0, f0.x, acc[2 * j]);
            acc[2 * j + 1] = fmaf(w0, f0.y, acc[2 * j + 1]);
        }
    }
    if (prev8) {
        U16 pv;
        pv.u = prev8[(size_t)r * 8 + li];
#pragma unroll
        for (int j = 0; j < 4; ++j) {
            float2 f = __half22float2(pv.h2[j]);
            acc[2 * j]     = fmaf(scale, acc[2 * j], -f.x);
            acc[2 * j + 1] = fmaf(scale, acc[2 * j + 1], -f.y);
        }
    }
    U16 res;
#pragma unroll
    for (int j = 0; j < 4; ++j)
        res.h2[j] = __float22half2_rn(make_float2(acc[2 * j], acc[2 * j + 1]));
    out8[(size_t)r * 8 + li] = res.u;
}

// Register-tiled GEMM: C[128 nodes x 128 h] per block, 256 threads (16x16),
// 8x8 microtile. A (fp16 Tx arrays) k=256 in 8 chunks of 32; B = cheb_w fp32.
// Thread tx covers h in {tx*4..+3} and {64+tx*4..+3} -> stride-4 lane pattern,
// 2-way LDS bank aliasing only (free). LDS 33KB -> 4 blocks/CU.
#define AS_LD 129
__global__ __launch_bounds__(256) void gemm_final(
        const uint4* __restrict__ tx0, const uint4* __restrict__ tx1,
        const uint4* __restrict__ tx2, const uint4* __restrict__ tx3,
        const float* __restrict__ W,       // [4, FIN, HDIM]
        const float* __restrict__ cheb_b, const float* __restrict__ fw,
        const float* __restrict__ fb, float* __restrict__ out, int n) {
    __shared__ float As[32 * AS_LD];   // As[k][node], k-chunk 32, +1 pad
    __shared__ float Bs[32 * HDIM];    // Bs[k][h]
    int tid = threadIdx.x;
    int tx = tid & 15, ty = tid >> 4;
    int nb0 = blockIdx.x * 128;

    float acc[8][8];
#pragma unroll
    for (int i = 0; i < 8; ++i)
#pragma unroll
        for (int j = 0; j < 8; ++j) acc[i][j] = 0.f;

    const uint4* txs[4] = {tx0, tx1, tx2, tx3};
    for (int c = 0; c < 8; ++c) {
        const uint4* arr = txs[c >> 1];
        int koff8 = (c & 1) * 4;           // uint4 offset within a 64-half row
        __syncthreads();
        // stage A chunk: 128 nodes x 32 k (fp16), transpose+cvt into As[k][node]
#pragma unroll
        for (int i = 0; i < 2; ++i) {
            int idx = tid + i * 256;       // 0..511
            int node = idx >> 2;
            int kk = (idx & 3) * 8;
            U16 v;
            if (nb0 + node < n) v.u = arr[(size_t)(nb0 + node) * 8 + koff8 + (idx & 3)];
            else v.u = make_uint4(0, 0, 0, 0);
#pragma unroll
            for (int j = 0; j < 4; ++j) {
                float2 f = __half22float2(v.h2[j]);
                As[(kk + 2 * j) * AS_LD + node] = f.x;
                As[(kk + 2 * j + 1) * AS_LD + node] = f.y;
            }
        }
        // stage B chunk: 32 k x 128 h contiguous from W
        {
            const float4* wsrc = (const float4*)(W + ((c >> 1) * FIN + (c & 1) * 32) * HDIM);
            float4* wdst = (float4*)Bs;
#pragma unroll
            for (int i = 0; i < 4; ++i) wdst[tid + i * 256] = wsrc[tid + i * 256];
        }
        __syncthreads();
#pragma unroll 8
        for (int k = 0; k < 32; ++k) {
            float av[8], bv[8];
            *(float4*)&av[0] = *(const float4*)&As[k * AS_LD + ty * 8];
            *(float4*)&av[4] = *(const float4*)&As[k * AS_LD + ty * 8 + 4];
            *(float4*)&bv[0] = *(const float4*)&Bs[k * HDIM + tx * 4];
            *(float4*)&bv[4] = *(const float4*)&Bs[k * HDIM + 64 + tx * 4];
#pragma unroll
            for (int i = 0; i < 8; ++i)
#pragma unroll
                for (int j = 0; j < 8; ++j)
                    acc[i][j] = fmaf(av[i], bv[j], acc[i][j]);
        }
    }
    // epilogue: per node s = sum_h tanh(acc+cb[h])*fw[h]; reduce over tx lanes
    float cb[8], fwv[8];
#pragma unroll
    for (int j = 0; j < 8; ++j) {
        int h = (j < 4) ? (tx * 4 + j) : (64 + tx * 4 + j - 4);
        cb[j] = cheb_b[h];
        fwv[j] = fw[h];
    }
    float fb0 = fb[0];
#pragma unroll
    for (int i = 0; i < 8; ++i) {
        float s = 0.f;
#pragma unroll
        for (int j = 0; j < 8; ++j)
            s = fmaf(tanhf(acc[i][j] + cb[j]), fwv[j], s);
        for (int m = 1; m < 16; m <<= 1) s += __shfl_xor(s, m, 64);
        if (tx == 0) {
            int node = nb0 + ty * 8 + i;
            if (node < n) out[node] = s + fb0;
        }
    }
}

extern "C" void kernel_launch(void* const* d_in, const int* in_sizes, int n_in,
                              void* d_out, int out_size, void* d_ws, size_t ws_size,
                              hipStream_t stream) {
    const float* features = (const float*)d_in[0];
    const int*   edge_index = (const int*)d_in[1];
    const float* cheb_w  = (const float*)d_in[2];
    const float* cheb_b  = (const float*)d_in[3];
    const float* final_w = (const float*)d_in[4];
    const float* final_b = (const float*)d_in[5];
    int N = in_sizes[0] / FIN;
    int E = in_sizes[1] / 2;
    const int* row = edge_index;        // edge_index[0, :]
    const int* col = edge_index + E;    // edge_index[1, :]

    char* p = (char*)d_ws;
    auto alloc = [&](size_t bytes) {
        char* r = p;
        p += (bytes + 255) & ~(size_t)255;
        return r;
    };
    int*   deg    = (int*)alloc((size_t)N * 4);
    float* dinv   = (float*)alloc((size_t)N * 4);
    int*   rowptr = (int*)alloc((size_t)(N + 1) * 4);
    int*   cursor = (int*)alloc((size_t)N * 4);
    int*   bsum   = (int*)alloc(1024 * 4);
    int2*  epk    = (int2*)alloc((size_t)E * 8);
    uint4* feath  = (uint4*)alloc((size_t)N * FIN * 2);   // fp16 rows
    uint4* tx1h   = (uint4*)alloc((size_t)N * FIN * 2);
    uint4* tx2h   = (uint4*)alloc((size_t)N * FIN * 2);
    uint4* tx3h   = (uint4*)alloc((size_t)N * FIN * 2);

    hipMemsetAsync(deg, 0, (size_t)N * 4, stream);
    count_deg<<<(E + 255) / 256, 256, 0, stream>>>(row, deg, E);
    make_dinv<<<(N + 255) / 256, 256, 0, stream>>>(deg, dinv, N);
    int n8 = N * FIN / 8;
    cvt_feat<<<(n8 + 255) / 256, 256, 0, stream>>>((const float4*)features, feath, n8);
    int nb = (N + 1023) / 1024;
    scan_local<<<nb, 1024, 0, stream>>>(deg, rowptr, bsum, N);
    scan_bsums<<<1, 64, 0, stream>>>(bsum, nb);
    scan_finish<<<(N + 1 + 255) / 256, 256, 0, stream>>>(rowptr, bsum, cursor, N, E);
    scatter_edges<<<(E + 255) / 256, 256, 0, stream>>>(row, col, dinv, cursor, epk, E);

    int waves = (N + 7) / 8;
    int spmm_blocks = (waves * 64 + 255) / 256;
    // Tx1 = L_hat @ x
    spmm_h<<<spmm_blocks, 256, 0, stream>>>(rowptr, epk, feath, nullptr, 1.f, tx1h, N);
    // Tx2 = 2 * L_hat @ Tx1 - Tx0
    spmm_h<<<spmm_blocks, 256, 0, stream>>>(rowptr, epk, tx1h, feath, 2.f, tx2h, N);
    // Tx3 = 2 * L_hat @ Tx2 - Tx1
    spmm_h<<<spmm_blocks, 256, 0, stream>>>(rowptr, epk, tx2h, tx1h, 2.f, tx3h, N);

    gemm_final<<<(N + 127) / 128, 256, 0, stream>>>(feath, tx1h, tx2h, tx3h, cheb_w,
                                                    cheb_b, final_w, final_b,
                                                    (float*)d_out, N);
}

// Round 4
// 231.670 us; speedup vs baseline: 2.7652x; 1.2069x over previous
//
#include <hip/hip_runtime.h>
#include <hip/hip_fp16.h>
#include <math.h>

// ChebConv (K=4) GNN head. N=50000, E=800000, F_IN=64, H=128.
// R4: MFMA (f32_16x16x32_f16) GEMM, LDS-free with pre-swizzled B fragments;
// SPMM gather loop unrolled 4x for MLP; fast tanh via __expf.

#define FIN 64
#define HDIM 128

typedef _Float16 half8 __attribute__((ext_vector_type(8)));
typedef float f32x4 __attribute__((ext_vector_type(4)));

union U16 { uint4 u; __half2 h2[4]; half8 h8; };

__global__ void count_deg(const int* __restrict__ row, int* __restrict__ deg, int E) {
    int e = blockIdx.x * blockDim.x + threadIdx.x;
    if (e < E) atomicAdd(&deg[row[e]], 1);
}

__global__ void make_dinv(const int* __restrict__ deg, float* __restrict__ dinv, int n) {
    int i = blockIdx.x * blockDim.x + threadIdx.x;
    if (i < n) {
        int d = deg[i];
        dinv[i] = (d > 0) ? rsqrtf((float)d) : 0.f;
    }
}

// features fp32 -> fp16 rows
__global__ void cvt_feat(const float4* __restrict__ src, uint4* __restrict__ dst, int n8) {
    int i = blockIdx.x * blockDim.x + threadIdx.x;
    if (i >= n8) return;
    float4 a = src[i * 2], b = src[i * 2 + 1];
    U16 v;
    v.h2[0] = __float22half2_rn(make_float2(a.x, a.y));
    v.h2[1] = __float22half2_rn(make_float2(a.z, a.w));
    v.h2[2] = __float22half2_rn(make_float2(b.x, b.y));
    v.h2[3] = __float22half2_rn(make_float2(b.z, b.w));
    dst[i] = v.u;
}

// Pre-swizzle cheb_w (viewed as B[256 k][128 h] fp32) into per-lane MFMA
// B-fragment order: Bfrag[(kk*8+ht)*64+lane] = 8 halfs B[kk*32+(lane>>4)*8+j][ht*16+(lane&15)]
__global__ void make_bfrag(const float* __restrict__ W, uint4* __restrict__ bfrag) {
    int t = blockIdx.x * blockDim.x + threadIdx.x;   // 0..4095
    if (t >= 8 * 8 * 64) return;
    int lane = t & 63;
    int ht = (t >> 6) & 7;
    int kk = t >> 9;
    int h = ht * 16 + (lane & 15);
    int kb = kk * 32 + (lane >> 4) * 8;
    U16 v;
#pragma unroll
    for (int j = 0; j < 4; ++j) {
        float a = W[(kb + 2 * j) * HDIM + h];
        float b = W[(kb + 2 * j + 1) * HDIM + h];
        v.h2[j] = __float22half2_rn(make_float2(a, b));
    }
    bfrag[t] = v.u;
}

// Per-block exclusive scan (Hillis-Steele over 1024 elems) + block totals.
__global__ void scan_local(const int* __restrict__ in, int* __restrict__ out,
                           int* __restrict__ bsum, int n) {
    __shared__ int buf[1024];
    int tid = threadIdx.x;
    int gid = blockIdx.x * 1024 + tid;
    int v = (gid < n) ? in[gid] : 0;
    int x = v;
    buf[tid] = x;
    __syncthreads();
    for (int off = 1; off < 1024; off <<= 1) {
        int t = (tid >= off) ? buf[tid - off] : 0;
        __syncthreads();
        x += t;
        buf[tid] = x;
        __syncthreads();
    }
    if (gid < n) out[gid] = x - v;
    if (tid == 1023) bsum[blockIdx.x] = x;
}

__global__ void scan_bsums(int* bsum, int nb) {
    if (blockIdx.x == 0 && threadIdx.x == 0) {
        int acc = 0;
        for (int b = 0; b < nb; ++b) { int t = bsum[b]; bsum[b] = acc; acc += t; }
    }
}

__global__ void scan_finish(int* __restrict__ rowptr, const int* __restrict__ bsum,
                            int* __restrict__ cursor, int n, int E) {
    int i = blockIdx.x * blockDim.x + threadIdx.x;
    if (i < n) {
        int v = rowptr[i] + bsum[i >> 10];
        rowptr[i] = v;
        cursor[i] = v;
    } else if (i == n) {
        rowptr[n] = E;
    }
}

__global__ void scatter_edges(const int* __restrict__ row, const int* __restrict__ col,
                              const float* __restrict__ dinv, int* __restrict__ cursor,
                              int2* __restrict__ epk, int E) {
    int e = blockIdx.x * blockDim.x + threadIdx.x;
    if (e < E) {
        int r = row[e], c = col[e];
        int p = atomicAdd(&cursor[r], 1);
        float w = -dinv[r] * dinv[c];   // L_hat = -D^-1/2 A D^-1/2
        epk[p] = make_int2(c, __float_as_int(w));
    }
}

// 8 rows/wave, 8 lanes/row, 16B (8 halfs) per lane, fp32 accumulate.
// Unroll 4 -> 4 outstanding gathers. out[r] = fp16(scale*sum - prev[r])
__global__ __launch_bounds__(256) void spmm_h(
        const int* __restrict__ rowptr, const int2* __restrict__ epk,
        const uint4* __restrict__ in8, const uint4* __restrict__ prev8,
        float scale, uint4* __restrict__ out8, int n) {
    int lane = threadIdx.x & 63;
    int wid = (blockIdx.x * blockDim.x + threadIdx.x) >> 6;
    int li = lane & 7, g = lane >> 3;
    int r = wid * 8 + g;
    if (r >= n) return;
    int s = rowptr[r], e = rowptr[r + 1];
    float acc[8];
#pragma unroll
    for (int j = 0; j < 8; ++j) acc[j] = 0.f;
    int p = s;
    for (; p + 4 <= e; p += 4) {
        int2 m0 = epk[p], m1 = epk[p + 1], m2 = epk[p + 2], m3 = epk[p + 3];
        U16 v0, v1, v2, v3;
        v0.u = in8[(size_t)m0.x * 8 + li];
        v1.u = in8[(size_t)m1.x * 8 + li];
        v2.u = in8[(size_t)m2.x * 8 + li];
        v3.u = in8[(size_t)m3.x * 8 + li];
        float w0 = __int_as_float(m0.y), w1 = __int_as_float(m1.y);
        float w2 = __int_as_float(m2.y), w3 = __int_as_float(m3.y);
#pragma unroll
        for (int j = 0; j < 4; ++j) {
            float2 f0 = __half22float2(v0.h2[j]);
            float2 f1 = __half22float2(v1.h2[j]);
            float2 f2 = __half22float2(v2.h2[j]);
            float2 f3 = __half22float2(v3.h2[j]);
            acc[2 * j]     = fmaf(w0, f0.x, acc[2 * j]);
            acc[2 * j + 1] = fmaf(w0, f0.y, acc[2 * j + 1]);
            acc[2 * j]     = fmaf(w1, f1.x, acc[2 * j]);
            acc[2 * j + 1] = fmaf(w1, f1.y, acc[2 * j + 1]);
            acc[2 * j]     = fmaf(w2, f2.x, acc[2 * j]);
            acc[2 * j + 1] = fmaf(w2, f2.y, acc[2 * j + 1]);
            acc[2 * j]     = fmaf(w3, f3.x, acc[2 * j]);
            acc[2 * j + 1] = fmaf(w3, f3.y, acc[2 * j + 1]);
        }
    }
    for (; p < e; ++p) {
        int2 m0 = epk[p];
        U16 v0;
        v0.u = in8[(size_t)m0.x * 8 + li];
        float w0 = __int_as_float(m0.y);
#pragma unroll
        for (int j = 0; j < 4; ++j) {
            float2 f0 = __half22float2(v0.h2[j]);
            acc[2 * j]     = fmaf(w0, f0.x, acc[2 * j]);
            acc[2 * j + 1] = fmaf(w0, f0.y, acc[2 * j + 1]);
        }
    }
    if (prev8) {
        U16 pv;
        pv.u = prev8[(size_t)r * 8 + li];
#pragma unroll
        for (int j = 0; j < 4; ++j) {
            float2 f = __half22float2(pv.h2[j]);
            acc[2 * j]     = fmaf(scale, acc[2 * j], -f.x);
            acc[2 * j + 1] = fmaf(scale, acc[2 * j + 1], -f.y);
        }
    }
    U16 res;
#pragma unroll
    for (int j = 0; j < 4; ++j)
        res.h2[j] = __float22half2_rn(make_float2(acc[2 * j], acc[2 * j + 1]));
    out8[(size_t)r * 8 + li] = res.u;
}

__device__ inline float tanh_fast(float x) {
    x = fmaxf(-10.f, fminf(10.f, x));
    float e = __expf(2.f * x);
    return (e - 1.f) / (e + 1.f);
}

// MFMA GEMM + tanh + final dot. Block = 256 thr = 4 waves; wave = 16 nodes x
// 128 h (8 tiles of 16x16, K=32/step, 8 steps over K=256). LDS-free:
// A frag = one 16B global load (A[m=lane&15][k=q*8+j], rows contiguous in k);
// B frags pre-swizzled in Bfrag (64KB, L1/L2-resident, coalesced 16B/lane).
// C layout: col(h)=lane&15, row=q*4+reg.
__global__ __launch_bounds__(256) void gemm_mfma(
        const uint4* __restrict__ tx0, const uint4* __restrict__ tx1,
        const uint4* __restrict__ tx2, const uint4* __restrict__ tx3,
        const uint4* __restrict__ bfrag,
        const float* __restrict__ cheb_b, const float* __restrict__ fw,
        const float* __restrict__ fb, float* __restrict__ out, int n) {
    int tid = threadIdx.x;
    int lane = tid & 63;
    int wave = tid >> 6;
    int q = lane >> 4, m = lane & 15;
    int node_base = blockIdx.x * 64 + wave * 16;
    int node = node_base + m;
    size_t nd = (node < n) ? (size_t)node : 0;   // clamp; store is guarded

    f32x4 acc[8];
#pragma unroll
    for (int t = 0; t < 8; ++t) acc[t] = (f32x4){0.f, 0.f, 0.f, 0.f};

    const uint4* txs[4] = {tx0, tx1, tx2, tx3};
#pragma unroll
    for (int kk = 0; kk < 8; ++kk) {
        U16 av;
        av.u = txs[kk >> 1][nd * 8 + (kk & 1) * 4 + q];
#pragma unroll
        for (int ht = 0; ht < 8; ++ht) {
            U16 bv;
            bv.u = bfrag[(kk * 8 + ht) * 64 + lane];
            acc[ht] = __builtin_amdgcn_mfma_f32_16x16x32_f16(av.h8, bv.h8, acc[ht], 0, 0, 0);
        }
    }

    // epilogue: s[reg] = sum_h tanh(acc + cb[h]) * fw[h]; reduce over 16 lanes
    float s[4] = {0.f, 0.f, 0.f, 0.f};
#pragma unroll
    for (int ht = 0; ht < 8; ++ht) {
        int h = ht * 16 + m;
        float cb = cheb_b[h];
        float fv = fw[h];
#pragma unroll
        for (int r = 0; r < 4; ++r)
            s[r] = fmaf(tanh_fast(acc[ht][r] + cb), fv, s[r]);
    }
#pragma unroll
    for (int r = 0; r < 4; ++r) {
        for (int msk = 1; msk < 16; msk <<= 1)
            s[r] += __shfl_xor(s[r], msk, 64);
    }
    if (m == 0) {
        float fb0 = fb[0];
#pragma unroll
        for (int r = 0; r < 4; ++r) {
            int o = node_base + q * 4 + r;
            if (o < n) out[o] = s[r] + fb0;
        }
    }
}

extern "C" void kernel_launch(void* const* d_in, const int* in_sizes, int n_in,
                              void* d_out, int out_size, void* d_ws, size_t ws_size,
                              hipStream_t stream) {
    const float* features = (const float*)d_in[0];
    const int*   edge_index = (const int*)d_in[1];
    const float* cheb_w  = (const float*)d_in[2];
    const float* cheb_b  = (const float*)d_in[3];
    const float* final_w = (const float*)d_in[4];
    const float* final_b = (const float*)d_in[5];
    int N = in_sizes[0] / FIN;
    int E = in_sizes[1] / 2;
    const int* row = edge_index;        // edge_index[0, :]
    const int* col = edge_index + E;    // edge_index[1, :]

    char* p = (char*)d_ws;
    auto alloc = [&](size_t bytes) {
        char* r = p;
        p += (bytes + 255) & ~(size_t)255;
        return r;
    };
    int*   deg    = (int*)alloc((size_t)N * 4);
    float* dinv   = (float*)alloc((size_t)N * 4);
    int*   rowptr = (int*)alloc((size_t)(N + 1) * 4);
    int*   cursor = (int*)alloc((size_t)N * 4);
    int*   bsum   = (int*)alloc(1024 * 4);
    int2*  epk    = (int2*)alloc((size_t)E * 8);
    uint4* feath  = (uint4*)alloc((size_t)N * FIN * 2);   // fp16 rows
    uint4* tx1h   = (uint4*)alloc((size_t)N * FIN * 2);
    uint4* tx2h   = (uint4*)alloc((size_t)N * FIN * 2);
    uint4* tx3h   = (uint4*)alloc((size_t)N * FIN * 2);
    uint4* bfrag  = (uint4*)alloc(4096 * 16);             // 64 KB B fragments

    hipMemsetAsync(deg, 0, (size_t)N * 4, stream);
    count_deg<<<(E + 255) / 256, 256, 0, stream>>>(row, deg, E);
    make_dinv<<<(N + 255) / 256, 256, 0, stream>>>(deg, dinv, N);
    int n8 = N * FIN / 8;
    cvt_feat<<<(n8 + 255) / 256, 256, 0, stream>>>((const float4*)features, feath, n8);
    make_bfrag<<<16, 256, 0, stream>>>(cheb_w, bfrag);
    int nb = (N + 1023) / 1024;
    scan_local<<<nb, 1024, 0, stream>>>(deg, rowptr, bsum, N);
    scan_bsums<<<1, 64, 0, stream>>>(bsum, nb);
    scan_finish<<<(N + 1 + 255) / 256, 256, 0, stream>>>(rowptr, bsum, cursor, N, E);
    scatter_edges<<<(E + 255) / 256, 256, 0, stream>>>(row, col, dinv, cursor, epk, E);

    int waves = (N + 7) / 8;
    int spmm_blocks = (waves * 64 + 255) / 256;
    // Tx1 = L_hat @ x
    spmm_h<<<spmm_blocks, 256, 0, stream>>>(rowptr, epk, feath, nullptr, 1.f, tx1h, N);
    // Tx2 = 2 * L_hat @ Tx1 - Tx0
    spmm_h<<<spmm_blocks, 256, 0, stream>>>(rowptr, epk, tx1h, feath, 2.f, tx2h, N);
    // Tx3 = 2 * L_hat @ Tx2 - Tx1
    spmm_h<<<spmm_blocks, 256, 0, stream>>>(rowptr, epk, tx2h, tx1h, 2.f, tx3h, N);

    gemm_mfma<<<(N + 63) / 64, 256, 0, stream>>>(feath, tx1h, tx2h, tx3h, bfrag,
                                                 cheb_b, final_w, final_b,
                                                 (float*)d_out, N);
}